// Round 2
// baseline (9151.136 us; speedup 1.0000x reference)
//
#include <hip/hip_runtime.h>

// PBRNN LSTM: B=64, S=512, D=544, H=1024. out = [h_n; c_n] fp32 [2,64,1024].
//
// Round 7 (resubmit — R1 bench was a GPUAcquisitionTimeout, no data):
// halve the h-exchange fan-out.
//  - 128 blocks x 512 threads (was 256x256): each block owns 32 cols x 4
//    gates for one 16-batch group. Exchange traffic drops 16 -> 8 MB/step.
//  - Fragments fetched ONCE per block: all 512 threads poll 4 tagged
//    32B fragments each (paired retry rounds), extract bf16, and hand off
//    through XOR-swizzled LDS h_s[16][1024]; the 8 waves ds_read their
//    MFMA B-fragments after one barrier (no redundant fabric reads).
//  - Gate partials reduced with ds_add_f32 into 17-padded gsum (conflict-
//    free update reads); 2 syncthreads/step; single h_s/gsum buffers are
//    race-free because barrier (B) precedes any thread reaching poll(t+1).
//  - Weights fully VGPR-pinned: whh 128 + wih 68 regs/thread (exact
//    floor for 32 cols/block at 512 threads). launch_bounds(512,2).

#define B_  64
#define S_  512
#define D_  544
#define H_  1024
#define NCG 32
#define BG_ 4
#define GRID_ (NCG*BG_)
#define THR_ 512

typedef __attribute__((ext_vector_type(8))) short bf16x8;
typedef __attribute__((ext_vector_type(4))) float f32x4;
typedef unsigned long long u64;

__device__ inline ushort f2b(float x){
  unsigned u = __float_as_uint(x);
  u = (u + 0x7FFFu + ((u >> 16) & 1u)) >> 16;   // RNE
  return (ushort)u;
}

__device__ inline bf16x8 pack8(float4 a, float4 b){
  bf16x8 r;
  r[0]=(short)f2b(a.x); r[1]=(short)f2b(a.y); r[2]=(short)f2b(a.z); r[3]=(short)f2b(a.w);
  r[4]=(short)f2b(b.x); r[5]=(short)f2b(b.y); r[6]=(short)f2b(b.z); r[7]=(short)f2b(b.w);
  return r;
}

__device__ inline u64 ld64a(const u64* q){
  return __hip_atomic_load(q, __ATOMIC_RELAXED, __HIP_MEMORY_SCOPE_AGENT);
}

__device__ inline float sigm(float x){ return __builtin_amdgcn_rcpf(1.f + __expf(-x)); }
__device__ inline float tanh_(float x){ return 1.f - 2.f*__builtin_amdgcn_rcpf(1.f + __expf(2.f*x)); }

__global__ void cvt_x(const float* __restrict__ x, ushort* __restrict__ xb, int n4){
  int i = blockIdx.x*256 + threadIdx.x;
  if (i >= n4) return;
  float4 v = ((const float4*)x)[i];
  ushort4 o;
  o.x=f2b(v.x); o.y=f2b(v.y); o.z=f2b(v.z); o.w=f2b(v.w);
  ((ushort4*)xb)[i] = o;
}

__global__ __launch_bounds__(THR_,2) void lstm_persist(
    const float* __restrict__ Wih, const float* __restrict__ Whh,
    const float* __restrict__ bih, const float* __restrict__ bhh,
    const ushort* __restrict__ Xb,
    unsigned* thbuf,       // [2][BG_][16384] tagged words, pre-zeroed
    float* __restrict__ out)
{
  const int tid  = threadIdx.x;
  const int wave = tid >> 6;
  const int lane = tid & 63;
  const int c16  = lane & 15;
  const int quad = lane >> 4;
  const int kq   = wave >> 1;     // K-quarter (256 of H)
  const int gh   = wave & 1;      // gate half: 0 -> {i,f}, 1 -> {g,o}

  // XCD-affinity: XCD = blockIdx%8; each bg's 32 blocks sit on 2 XCDs
  const int bg = (blockIdx.x & 7) >> 1;
  const int cg = ((blockIdx.x >> 3) << 1) | (blockIdx.x & 1);   // 0..31

  __shared__ __align__(16) char h_s[16*1024*2];   // [batch][K] bf16, byte ^= (b&7)<<4
  __shared__ float gsum[4][32][17];               // [gate][col][batch+pad]

  // ---- W_hh fragments: 2 gates x 2 col-blocks x 8 K-iters (128 VGPR) ----
  bf16x8 whhf[2][2][8];
  #pragma unroll
  for (int g2 = 0; g2 < 2; ++g2){
    #pragma unroll
    for (int cb = 0; cb < 2; ++cb){
      const size_t grow = (size_t)((gh*2+g2)*H_ + cg*32 + cb*16 + c16);
      #pragma unroll
      for (int i = 0; i < 8; ++i){
        int k = kq*256 + i*32 + quad*8;
        const float4* p = (const float4*)(Whh + grow*H_ + k);
        whhf[g2][cb][i] = pack8(p[0], p[1]);
      }
    }
  }
  // ---- W_ih fragments: iters it = kq+4*ii (ii<4); iter 16 -> one (g2,cb)/kq ----
  bf16x8 wihf[2][2][4];
  #pragma unroll
  for (int g2 = 0; g2 < 2; ++g2){
    #pragma unroll
    for (int cb = 0; cb < 2; ++cb){
      const size_t grow = (size_t)((gh*2+g2)*H_ + cg*32 + cb*16 + c16);
      #pragma unroll
      for (int ii = 0; ii < 4; ++ii){
        int k = (kq + 4*ii)*32 + quad*8;
        const float4* p = (const float4*)(Wih + grow*D_ + k);
        wihf[g2][cb][ii] = pack8(p[0], p[1]);
      }
    }
  }
  bf16x8 wihf16;
  {
    const size_t grow = (size_t)((gh*2 + (kq>>1))*H_ + cg*32 + (kq&1)*16 + c16);
    const float4* p = (const float4*)(Wih + grow*D_ + 512 + quad*8);
    wihf16 = pack8(p[0], p[1]);
  }

  // ---- update mapping: thread owns (batch ub, col ucol) ----
  const int ucol = tid & 31;
  const int ub   = tid >> 5;
  float bsum[4];
  #pragma unroll
  for (int g = 0; g < 4; ++g)
    bsum[g] = bih[g*H_ + cg*32 + ucol] + bhh[g*H_ + cg*32 + ucol];
  float cstate = 0.f;

  #pragma unroll
  for (int g = 0; g < 4; ++g) gsum[g][ucol][ub] = 0.f;   // (A)@t=0 orders this

  f32x4 acc[2][2];
  bf16x8 xraw[4]; bf16x8 xraw16;

  auto zacc = [&]{
    #pragma unroll
    for (int g2 = 0; g2 < 2; ++g2)
      #pragma unroll
      for (int cb = 0; cb < 2; ++cb) acc[g2][cb] = (f32x4){0.f,0.f,0.f,0.f};
  };
  auto ldx = [&](int t){
    const ushort* xrow = Xb + ((size_t)(bg*16 + c16)*S_ + t)*D_;
    #pragma unroll
    for (int ii = 0; ii < 4; ++ii)
      xraw[ii] = *(const bf16x8*)(xrow + (kq + 4*ii)*32 + quad*8);
    xraw16 = *(const bf16x8*)(xrow + 512 + quad*8);
  };
  auto xp_mfma = [&]{
    #pragma unroll
    for (int ii = 0; ii < 4; ++ii)
      #pragma unroll
      for (int g2 = 0; g2 < 2; ++g2)
        #pragma unroll
        for (int cb = 0; cb < 2; ++cb)
          acc[g2][cb] = __builtin_amdgcn_mfma_f32_16x16x32_bf16(wihf[g2][cb][ii], xraw[ii], acc[g2][cb], 0,0,0);
    // iter 16: static acc index per kq (runtime-indexed reg arrays spill)
    if      (kq==0) acc[0][0] = __builtin_amdgcn_mfma_f32_16x16x32_bf16(wihf16, xraw16, acc[0][0], 0,0,0);
    else if (kq==1) acc[0][1] = __builtin_amdgcn_mfma_f32_16x16x32_bf16(wihf16, xraw16, acc[0][1], 0,0,0);
    else if (kq==2) acc[1][0] = __builtin_amdgcn_mfma_f32_16x16x32_bf16(wihf16, xraw16, acc[1][0], 0,0,0);
    else            acc[1][1] = __builtin_amdgcn_mfma_f32_16x16x32_bf16(wihf16, xraw16, acc[1][1], 0,0,0);
  };

  // prologue: acc = xp(0)
  ldx(0);
  zacc();
  xp_mfma();

  for (int t = 0; t < S_; ++t){
    const unsigned* hp = thbuf + (t & 1) * (B_*H_);
    unsigned*       hn = thbuf + ((t & 1) ^ 1) * (B_*H_);
    const unsigned tag = (unsigned)t & 0xffffu;
    const u64 tmask = 0xffff0000ffff0000ull;
    const u64 texp  = ((u64)tag << 16) | ((u64)tag << 48);

    // ---- 1. poll bg slab: 2048 frags x 32B, 4/thread, fetched ONCE/block ----
    #pragma unroll
    for (int pair = 0; pair < 2; ++pair){
      u64 q[2][4];
      const u64* pb[2];
      #pragma unroll
      for (int f = 0; f < 2; ++f){
        int F = (pair*2 + f)*THR_ + tid;
        pb[f] = (const u64*)(hp + bg*16384 + F*8);
        q[f][0]=ld64a(pb[f]);   q[f][1]=ld64a(pb[f]+1);
        q[f][2]=ld64a(pb[f]+2); q[f][3]=ld64a(pb[f]+3);
      }
      unsigned stale = 3u;
      int rounds = 0;
      while (stale){
        unsigned ns = 0;
        #pragma unroll
        for (int f = 0; f < 2; ++f){
          if (stale & (1u<<f)){
            u64 d = ((q[f][0]^texp)|(q[f][1]^texp)|(q[f][2]^texp)|(q[f][3]^texp)) & tmask;
            if (d != 0ull){
              q[f][0]=ld64a(pb[f]);   q[f][1]=ld64a(pb[f]+1);
              q[f][2]=ld64a(pb[f]+2); q[f][3]=ld64a(pb[f]+3);
              ns |= (1u<<f);
            }
          }
        }
        stale = ns;
        if (++rounds > (1<<20)) break;   // safety: never hang the harness
      }
      // extract payload -> swizzled LDS handoff
      #pragma unroll
      for (int f = 0; f < 2; ++f){
        int F  = (pair*2 + f)*THR_ + tid;
        int b  = (F >> 1) & 15;
        int k0 = (F >> 5)*16 + (F & 1)*8;
        uint4 pv;
        pv.x = (unsigned)(q[f][0] & 0xffffu) | (unsigned)((q[f][0] >> 16) & 0xffff0000u);
        pv.y = (unsigned)(q[f][1] & 0xffffu) | (unsigned)((q[f][1] >> 16) & 0xffff0000u);
        pv.z = (unsigned)(q[f][2] & 0xffffu) | (unsigned)((q[f][2] >> 16) & 0xffff0000u);
        pv.w = (unsigned)(q[f][3] & 0xffffu) | (unsigned)((q[f][3] >> 16) & 0xffff0000u);
        int byte = (b*2048 + k0*2) ^ ((b & 7) << 4);
        *(uint4*)(h_s + byte) = pv;
      }
    }
    __syncthreads();                        // (A) h_s complete

    // ---- 2. hh MFMA: B-frags from swizzled LDS ----
    #pragma unroll
    for (int i = 0; i < 8; ++i){
      int byte = (c16*2048 + kq*512 + i*64 + quad*16) ^ ((c16 & 7) << 4);
      bf16x8 hb = *(const bf16x8*)(h_s + byte);
      #pragma unroll
      for (int g2 = 0; g2 < 2; ++g2)
        #pragma unroll
        for (int cb = 0; cb < 2; ++cb)
          acc[g2][cb] = __builtin_amdgcn_mfma_f32_16x16x32_bf16(whhf[g2][cb][i], hb, acc[g2][cb], 0,0,0);
    }
    // ---- 3. K-quarter reduction via LDS atomic adds ----
    #pragma unroll
    for (int g2 = 0; g2 < 2; ++g2)
      #pragma unroll
      for (int cb = 0; cb < 2; ++cb)
        #pragma unroll
        for (int r = 0; r < 4; ++r)
          atomicAdd(&gsum[gh*2+g2][cb*16 + quad*4 + r][c16], acc[g2][cb][r]);
    __syncthreads();                        // (B) gsum complete; h_s reads done

    // ---- 4. update: X(t+1) loads fly under the nonlinearity ----
    if (t < S_-1) ldx(t+1);
    float gs[4];
    #pragma unroll
    for (int g = 0; g < 4; ++g) gs[g] = bsum[g] + gsum[g][ucol][ub];
    #pragma unroll
    for (int g = 0; g < 4; ++g) gsum[g][ucol][ub] = 0.f;   // re-arm for t+1
    float iv = sigm(gs[0]), fv = sigm(gs[1]), gv = tanh_(gs[2]), ov = sigm(gs[3]);
    float cn = fv*cstate + iv*gv;
    cstate = cn;
    float hv = ov*tanh_(cn);
    unsigned word = (((unsigned)(t+1) & 0xffffu) << 16) | (unsigned)f2b(hv);
    int colg = cg*32 + ucol;
    __hip_atomic_store(hn + bg*16384 + (colg >> 4)*256 + ub*16 + (colg & 15), word,
                       __ATOMIC_RELAXED, __HIP_MEMORY_SCOPE_AGENT);
    if (t == S_-1){
      out[(bg*16 + ub)*H_ + colg]          = hv;   // h_n
      out[B_*H_ + (bg*16 + ub)*H_ + colg]  = cn;   // c_n
    } else {
      zacc();
      xp_mfma();     // xp(t+1) ready before poll(t+1)
    }
  }
}

extern "C" void kernel_launch(void* const* d_in, const int* in_sizes, int n_in,
                              void* d_out, int out_size, void* d_ws, size_t ws_size,
                              hipStream_t stream) {
  const float* X   = (const float*)d_in[0];
  const float* Wih = (const float*)d_in[1];
  const float* Whh = (const float*)d_in[2];
  const float* bih = (const float*)d_in[3];
  const float* bhh = (const float*)d_in[4];
  float* out = (float*)d_out;

  // ws layout: [0, 512KB) tagged h double buffer, [512KB, +35.7MB) X bf16.
  char* ws = (char*)d_ws;
  const size_t THBUF_BYTES = 2ull * B_ * H_ * sizeof(unsigned);     // 524288
  const size_t XB_OFF      = THBUF_BYTES;
  const size_t XB_BYTES    = (size_t)B_ * S_ * D_ * sizeof(ushort); // 35.65 MB
  if (ws_size < XB_OFF + XB_BYTES) return;  // insufficient scratch: fail visibly

  unsigned* thbuf = (unsigned*)ws;
  ushort*   Xb    = (ushort*)(ws + XB_OFF);

  hipMemsetAsync(d_ws, 0, THBUF_BYTES, stream);   // tags=0, h0=0

  int n4 = B_*S_*D_/4;
  cvt_x<<<(n4 + 255)/256, 256, 0, stream>>>(X, Xb, n4);
  lstm_persist<<<GRID_, THR_, 0, stream>>>(Wih, Whh, bih, bhh, Xb, thbuf, out);
}